// Round 11
// baseline (213.938 us; speedup 1.0000x reference)
//
#include <hip/hip_runtime.h>

#define NN 50000
#define EE 800000
#define HH 128
#define CC 10
#define GG 128
#define NBK 782      // ceil(NN/64) buckets = GEMM tiles
#define NCH 98       // ceil(EE/8192) edge chunks
#define CHUNK 8192

typedef __attribute__((ext_vector_type(8))) short short8;
typedef __attribute__((ext_vector_type(4))) float f32x4;

// ---------- bf16 helpers (RNE) ----------
__device__ __forceinline__ ushort f2b(float f) {
    union { float f; uint u; } x; x.f = f;
    uint u = x.u;
    uint r = (u + 0x7fffu + ((u >> 16) & 1u)) >> 16;
    return (ushort)r;
}
__device__ __forceinline__ float lo2f(uint v) {
    union { uint u; float f; } x; x.u = v << 16; return x.f;
}
__device__ __forceinline__ float hi2f(uint v) {
    union { uint u; float f; } x; x.u = v & 0xffff0000u; return x.f;
}

// ---------------- prep: f2b + wconv + hist + hg-zero + counter-zero -------------
// blocks [0,6250): f2b  [6250,6634): wconv  [6634,6732): hist  [6732,6796): hg=0

__global__ __launch_bounds__(256) void prep_kernel(const float* __restrict__ features,
                                                   const float* w0, const float* w1,
                                                   const float* w2, const float* w3,
                                                   const float* w4, const float* w5,
                                                   const int* __restrict__ dst,
                                                   ushort* __restrict__ hb0,
                                                   ushort* __restrict__ wt,
                                                   int* __restrict__ hist,
                                                   float* __restrict__ hg,
                                                   int* __restrict__ counter) {
    __shared__ int hc[NBK];
    const int b = blockIdx.x, t = threadIdx.x;
    if (b < 6250) {
        int idx = b * 256 + t;              // 1.6M quads exactly
        float4 v = *(const float4*)(features + (size_t)idx * 4);
        ushort4 o;
        o.x = f2b(v.x); o.y = f2b(v.y); o.z = f2b(v.z); o.w = f2b(v.w);
        *(ushort4*)(hb0 + (size_t)idx * 4) = o;
    } else if (b < 6634) {
        int idx = (b - 6250) * 256 + t;     // 0..98303
        int mi = idx >> 14, rest = idx & 16383;
        int n = rest >> 7, k = rest & 127;
        const float* src;
        switch (mi) {
            case 0: src = w0; break; case 1: src = w1; break;
            case 2: src = w2; break; case 3: src = w3; break;
            case 4: src = w4; break; default: src = w5; break;
        }
        wt[mi * 16384 + n * 128 + k] = f2b(src[k * 128 + n]);
    } else if (b < 6732) {
        const int c = b - 6634;
        for (int k = t; k < NBK; k += 256) hc[k] = 0;
        __syncthreads();
        for (int j = 0; j < 32; ++j) {
            int e = c * CHUNK + j * 256 + t;
            if (e < EE) atomicAdd(&hc[dst[e] >> 6], 1);
        }
        __syncthreads();
        for (int k = t; k < NBK; k += 256) hist[k * NCH + c] = hc[k];  // bucket-major
    } else {
        int idx = (b - 6732) * 256 + t;     // 16384 floats exactly
        hg[idx] = 0.f;
        if (b == 6732 && t == 0) *counter = 0;
    }
}

// per-bucket scan of chunk counts -> rel offsets; bucket base via atomic alloc
__global__ __launch_bounds__(128) void bscan_kernel(const int* __restrict__ hist,
                                                    int* __restrict__ rel,
                                                    int* __restrict__ btot,
                                                    int* __restrict__ bucketbase,
                                                    int* __restrict__ counter) {
    __shared__ int s[128];
    const int b = blockIdx.x, t = threadIdx.x;
    int v = (t < NCH) ? hist[b * NCH + t] : 0;
    s[t] = v;
    __syncthreads();
    for (int off = 1; off < 128; off <<= 1) {
        int tt = (t >= off) ? s[t - off] : 0;
        __syncthreads();
        s[t] += tt;
        __syncthreads();
    }
    if (t < NCH) rel[b * NCH + t] = s[t] - v;   // exclusive
    if (t == 127) {
        btot[b] = s[127];
        bucketbase[b] = atomicAdd(counter, s[127]);
    }
}

// scatter edges into bucket-contiguous packed lists: (dstLocal<<16)|src
__global__ __launch_bounds__(256) void scatter_kernel(const int* __restrict__ src,
                                                      const int* __restrict__ dst,
                                                      const int* __restrict__ rel,
                                                      const int* __restrict__ bucketbase,
                                                      int* __restrict__ epk) {
    __shared__ int cur[NBK];
    const int c = blockIdx.x, t = threadIdx.x;
    for (int k = t; k < NBK; k += 256) cur[k] = bucketbase[k] + rel[k * NCH + c];
    __syncthreads();
    for (int j = 0; j < 32; ++j) {
        int e = c * CHUNK + j * 256 + t;
        if (e < EE) {
            int d = dst[e];
            int bk = d >> 6;
            int pos = atomicAdd(&cur[bk], 1);
            epk[pos] = ((d & 63) << 16) | src[e];
        }
    }
}

// per-bucket counting sort -> node-ordered eidx + per-node [rowbeg,rowend)
__global__ __launch_bounds__(256) void bsort_kernel(const int* __restrict__ epk,
                                                    const int* __restrict__ bucketbase,
                                                    const int* __restrict__ btot,
                                                    ushort* __restrict__ eidx,
                                                    int* __restrict__ rowbeg,
                                                    int* __restrict__ rowend) {
    __shared__ int cnt[64];
    __shared__ int cur[64];
    const int b = blockIdx.x, t = threadIdx.x;
    const int base = bucketbase[b], end = base + btot[b];
    if (t < 64) cnt[t] = 0;
    __syncthreads();
    for (int i = base + t; i < end; i += 256)
        atomicAdd(&cnt[(epk[i] >> 16) & 63], 1);
    __syncthreads();
    if (t < 64) {
        int v = cnt[t];
        int incl = v;
#pragma unroll
        for (int off = 1; off < 64; off <<= 1) {
            int u = __shfl_up(incl, off);
            if (t >= off) incl += u;
        }
        int excl = incl - v;
        cur[t] = excl;
        int node = b * 64 + t;
        if (node < NN) {
            rowbeg[node] = base + excl;
            rowend[node] = base + incl;
        }
    }
    __syncthreads();
    for (int i = base + t; i < end; i += 256) {
        int p = epk[i];
        int dl = (p >> 16) & 63;
        int pos = atomicAdd(&cur[dl], 1);
        eidx[base + pos] = (ushort)(p & 0xffff);
    }
}

// ---------------- aggregation: half-wave per node, 8-deep + predicated tail --------
// xb[n] = bf16((1+eps)*h[n] + sum_neighbors h[s])

__global__ __launch_bounds__(256) void aggregate_kernel(const ushort* __restrict__ h,
                                                        const int* __restrict__ rowbeg,
                                                        const int* __restrict__ rowend,
                                                        const ushort* __restrict__ eidx,
                                                        const float* __restrict__ epsp,
                                                        int layer,
                                                        ushort* __restrict__ xb) {
    const int node = blockIdx.x * 8 + (threadIdx.x >> 5);
    if (node >= NN) return;
    const int li = threadIdx.x & 31;
    const int beg = rowbeg[node], end = rowend[node];
    float c0 = 0.f, c1 = 0.f, c2 = 0.f, c3 = 0.f;
    int i = beg;
    for (; i + 8 <= end; i += 8) {
        int s[8];
        uint2 v[8];
#pragma unroll
        for (int k = 0; k < 8; ++k) s[k] = eidx[i + k];
#pragma unroll
        for (int k = 0; k < 8; ++k)
            v[k] = *(const uint2*)(h + (size_t)s[k] * HH + li * 4);
#pragma unroll
        for (int k = 0; k < 8; ++k) {
            c0 += lo2f(v[k].x); c1 += hi2f(v[k].x);
            c2 += lo2f(v[k].y); c3 += hi2f(v[k].y);
        }
    }
    if (i < end) {
        int s[8];
        uint2 v[8];
#pragma unroll
        for (int k = 0; k < 8; ++k) {
            int idx = i + k;
            s[k] = eidx[idx < end ? idx : end - 1];
        }
#pragma unroll
        for (int k = 0; k < 8; ++k)
            v[k] = *(const uint2*)(h + (size_t)s[k] * HH + li * 4);
#pragma unroll
        for (int k = 0; k < 8; ++k) {
            if (i + k < end) {
                c0 += lo2f(v[k].x); c1 += hi2f(v[k].x);
                c2 += lo2f(v[k].y); c3 += hi2f(v[k].y);
            }
        }
    }
    uint2 hv = *(const uint2*)(h + (size_t)node * HH + li * 4);
    const float e = 1.0f + epsp[layer];
    ushort4 o;
    o.x = f2b(e * lo2f(hv.x) + c0);
    o.y = f2b(e * hi2f(hv.x) + c1);
    o.z = f2b(e * lo2f(hv.y) + c2);
    o.w = f2b(e * hi2f(hv.y) + c3);
    *(ushort4*)(xb + (size_t)node * HH + li * 4) = o;
}

// ---------------- fused MLP: 512 threads, 8 waves, 2 concurrent 64-row tiles ------
// Wave-group g in {0,1} owns tile g (rows row0+g*64 ..+63). Each wave handles 32
// output cols. 2 barriers total. LAST: outputs -> xs[g] LDS -> pooled into hg.

template <bool LAST>
__global__ __launch_bounds__(512) void fused_mlp(const ushort* __restrict__ xb,
                                                 const ushort* __restrict__ wt1,  // [n][k]
                                                 const ushort* __restrict__ wt2,  // [n][k]
                                                 const float* __restrict__ b1,
                                                 const float* __restrict__ b2,
                                                 const int* __restrict__ gid,
                                                 float* __restrict__ hg,
                                                 ushort* __restrict__ out, int nrows) {
    __shared__ __align__(16) ushort xs[2][64][136];
    __shared__ __align__(16) ushort hs[2][64][136];
    const int tid = threadIdx.x;
    const int lane = tid & 63;
    const int w = (tid >> 6) & 3;      // wave-in-group: output col range
    const int g = tid >> 8;            // tile group 0/1
    const int row0 = blockIdx.x * 128 + g * 64;
    const int l15 = lane & 15, lhi = lane >> 4;
    const int gt = tid & 255;          // thread index within group
    const int sr = gt >> 4, skq = gt & 15;

    // ---- stage tile g (256 threads per group; 4 rows each) ----
#pragma unroll
    for (int it = 0; it < 4; ++it) {
        int r = it * 16 + sr;
        int row = row0 + r;
        uint4 xv = make_uint4(0u, 0u, 0u, 0u);
        if (row < nrows) xv = *(const uint4*)(xb + (size_t)row * HH + skq * 8);
        *(uint4*)&xs[g][r][skq * 8] = xv;
    }

    // ---- W fragments (L2-hot), per wave ----
    short8 a1[2][4], a2[2][4];
#pragma unroll
    for (int fa = 0; fa < 2; ++fa)
#pragma unroll
        for (int kt = 0; kt < 4; ++kt) {
            int n = w * 32 + fa * 16 + l15;
            int k = kt * 32 + lhi * 8;
            a1[fa][kt] = *(const short8*)(wt1 + n * HH + k);
            a2[fa][kt] = *(const short8*)(wt2 + n * HH + k);
        }
    __syncthreads();

    // ---- GEMM1 ----
    f32x4 acc[2][4];
#pragma unroll
    for (int fa = 0; fa < 2; ++fa)
#pragma unroll
        for (int fb = 0; fb < 4; ++fb) acc[fa][fb] = (f32x4)(0.f);
#pragma unroll
    for (int kt = 0; kt < 4; ++kt) {
        short8 bfr[4];
#pragma unroll
        for (int fb = 0; fb < 4; ++fb)
            bfr[fb] = *(const short8*)&xs[g][fb * 16 + l15][kt * 32 + lhi * 8];
#pragma unroll
        for (int fa = 0; fa < 2; ++fa)
#pragma unroll
            for (int fb = 0; fb < 4; ++fb)
                acc[fa][fb] = __builtin_amdgcn_mfma_f32_16x16x32_bf16(a1[fa][kt], bfr[fb],
                                                                     acc[fa][fb], 0, 0, 0);
    }

    // hidden = relu(acc + b1) -> hs[g]
#pragma unroll
    for (int fa = 0; fa < 2; ++fa) {
        int nb = w * 32 + fa * 16 + lhi * 4;
        float4 bv = *(const float4*)(b1 + nb);
#pragma unroll
        for (int fb = 0; fb < 4; ++fb) {
            ushort4 o;
            o.x = f2b(fmaxf(acc[fa][fb][0] + bv.x, 0.f));
            o.y = f2b(fmaxf(acc[fa][fb][1] + bv.y, 0.f));
            o.z = f2b(fmaxf(acc[fa][fb][2] + bv.z, 0.f));
            o.w = f2b(fmaxf(acc[fa][fb][3] + bv.w, 0.f));
            *(ushort4*)&hs[g][fb * 16 + l15][nb] = o;
        }
    }
    __syncthreads();

    // ---- GEMM2 ----
#pragma unroll
    for (int fa = 0; fa < 2; ++fa)
#pragma unroll
        for (int fb = 0; fb < 4; ++fb) acc[fa][fb] = (f32x4)(0.f);
#pragma unroll
    for (int kt = 0; kt < 4; ++kt) {
        short8 bfr[4];
#pragma unroll
        for (int fb = 0; fb < 4; ++fb)
            bfr[fb] = *(const short8*)&hs[g][fb * 16 + l15][kt * 32 + lhi * 8];
#pragma unroll
        for (int fa = 0; fa < 2; ++fa)
#pragma unroll
            for (int fb = 0; fb < 4; ++fb)
                acc[fa][fb] = __builtin_amdgcn_mfma_f32_16x16x32_bf16(a2[fa][kt], bfr[fb],
                                                                     acc[fa][fb], 0, 0, 0);
    }

    // ---- epilogue ----
#pragma unroll
    for (int fa = 0; fa < 2; ++fa) {
        int nb = w * 32 + fa * 16 + lhi * 4;
        float4 bv = *(const float4*)(b2 + nb);
#pragma unroll
        for (int fb = 0; fb < 4; ++fb) {
            int m = row0 + fb * 16 + l15;
            ushort4 o;
            o.x = f2b(fmaxf(acc[fa][fb][0] + bv.x, 0.f));
            o.y = f2b(fmaxf(acc[fa][fb][1] + bv.y, 0.f));
            o.z = f2b(fmaxf(acc[fa][fb][2] + bv.z, 0.f));
            o.w = f2b(fmaxf(acc[fa][fb][3] + bv.w, 0.f));
            if (LAST) {
                *(ushort4*)&xs[g][fb * 16 + l15][nb] = o;   // xs[g] free after GEMM1
            } else if (m < nrows) {
                *(ushort4*)(out + (size_t)m * HH + nb) = o;
            }
        }
    }

    if (LAST) {
        __syncthreads();
        // pool group's 64 rows from xs[g] into hg (gid sorted -> runs + atomic flush)
        int j = gt & 63;
        int rg = gt >> 6;
        float ax = 0.f, ay = 0.f;
        int gcur = -1;
#pragma unroll
        for (int ii = 0; ii < 16; ++ii) {
            int r = rg + ii * 4;
            int n = row0 + r;
            if (n >= nrows) break;
            int gv = gid[n];
            if (gv != gcur) {
                if (gcur >= 0) {
                    atomicAdd(&hg[gcur * HH + 2 * j], ax);
                    atomicAdd(&hg[gcur * HH + 2 * j + 1], ay);
                }
                gcur = gv; ax = 0.f; ay = 0.f;
            }
            uint v = *(const uint*)&xs[g][r][2 * j];
            ax += lo2f(v); ay += hi2f(v);
        }
        if (gcur >= 0) {
            atomicAdd(&hg[gcur * HH + 2 * j], ax);
            atomicAdd(&hg[gcur * HH + 2 * j + 1], ay);
        }
    }
}

// ---------------- classifier head (fp32) ----------------

__global__ __launch_bounds__(128) void classify_kernel(const float* __restrict__ hg,
                                                       const float* __restrict__ wc1,
                                                       const float* __restrict__ bc1,
                                                       const float* __restrict__ wc2,
                                                       const float* __restrict__ bc2,
                                                       float* __restrict__ out) {
    __shared__ float xrow[HH];
    __shared__ float trow[HH];
    int g = blockIdx.x, j = threadIdx.x;
    xrow[j] = hg[g * HH + j];
    __syncthreads();
    float s = bc1[j];
#pragma unroll 8
    for (int k = 0; k < HH; ++k) s += xrow[k] * wc1[k * HH + j];
    trow[j] = fmaxf(s, 0.f);
    __syncthreads();
    if (j < CC) {
        float o = bc2[j];
#pragma unroll 8
        for (int k = 0; k < HH; ++k) o += trow[k] * wc2[k * CC + j];
        out[g * CC + j] = o;
    }
}

extern "C" void kernel_launch(void* const* d_in, const int* in_sizes, int n_in,
                              void* d_out, int out_size, void* d_ws, size_t ws_size,
                              hipStream_t stream) {
    const float* features = (const float*)d_in[0];
    const int* src = (const int*)d_in[1];
    const int* dst = (const int*)d_in[2];
    const int* gid = (const int*)d_in[3];
    const float* eps = (const float*)d_in[4];
    const float* w1[3] = {(const float*)d_in[5], (const float*)d_in[9], (const float*)d_in[13]};
    const float* b1[3] = {(const float*)d_in[6], (const float*)d_in[10], (const float*)d_in[14]};
    const float* w2[3] = {(const float*)d_in[7], (const float*)d_in[11], (const float*)d_in[15]};
    const float* b2[3] = {(const float*)d_in[8], (const float*)d_in[12], (const float*)d_in[16]};
    const float* wc1 = (const float*)d_in[17];
    const float* bc1 = (const float*)d_in[18];
    const float* wc2 = (const float*)d_in[19];
    const float* bc2 = (const float*)d_in[20];
    float* outp = (float*)d_out;

    char* ws = (char*)d_ws;
    size_t off = 0;
    auto alloc = [&](size_t bytes) {
        void* p = ws + off;
        off += (bytes + 255) & ~(size_t)255;
        return p;
    };
    int* hist = (int*)alloc((size_t)NBK * NCH * sizeof(int));
    int* rel = (int*)alloc((size_t)NBK * NCH * sizeof(int));
    int* btot = (int*)alloc(NBK * sizeof(int));
    int* bucketbase = (int*)alloc(NBK * sizeof(int));
    int* counter = (int*)alloc(256);
    int* epk = (int*)alloc(EE * sizeof(int));
    ushort* eidx = (ushort*)alloc(EE * sizeof(ushort));
    int* rowbeg = (int*)alloc(NN * sizeof(int));
    int* rowend = (int*)alloc(NN * sizeof(int));
    ushort* hb0 = (ushort*)alloc((size_t)NN * HH * 2);    // features bf16
    ushort* hbuf = (ushort*)alloc((size_t)NN * HH * 2);   // layer h bf16
    ushort* xb = (ushort*)alloc((size_t)NN * HH * 2);     // combined MLP input bf16
    ushort* wtb = (ushort*)alloc(6 * 16384 * 2);          // transposed bf16 weights
    float* hg = (float*)alloc(GG * HH * sizeof(float));

    // prep (f2b + wconv + hist + hg/counter zero) then bucketed CSR build
    prep_kernel<<<6796, 256, 0, stream>>>(features, w1[0], w2[0], w1[1], w2[1], w1[2], w2[2],
                                          dst, hb0, wtb, hist, hg, counter);
    bscan_kernel<<<NBK, 128, 0, stream>>>(hist, rel, btot, bucketbase, counter);
    scatter_kernel<<<NCH, 256, 0, stream>>>(src, dst, rel, bucketbase, epk);
    bsort_kernel<<<NBK, 256, 0, stream>>>(epk, bucketbase, btot, eidx, rowbeg, rowend);

    const int GB = (NN + 127) / 128;  // 391
    const int AB = (NN + 7) / 8;      // 6250

    // layer 1
    aggregate_kernel<<<AB, 256, 0, stream>>>(hb0, rowbeg, rowend, eidx, eps, 0, xb);
    fused_mlp<false><<<GB, 512, 0, stream>>>(xb, wtb + 0 * 16384, wtb + 1 * 16384,
                                             b1[0], b2[0], gid, hg, hbuf, NN);
    // layer 2
    aggregate_kernel<<<AB, 256, 0, stream>>>(hbuf, rowbeg, rowend, eidx, eps, 1, xb);
    fused_mlp<false><<<GB, 512, 0, stream>>>(xb, wtb + 2 * 16384, wtb + 3 * 16384,
                                             b1[1], b2[1], gid, hg, hbuf, NN);
    // layer 3 (pool fused into epilogue; no h write)
    aggregate_kernel<<<AB, 256, 0, stream>>>(hbuf, rowbeg, rowend, eidx, eps, 2, xb);
    fused_mlp<true><<<GB, 512, 0, stream>>>(xb, wtb + 4 * 16384, wtb + 5 * 16384,
                                            b1[2], b2[2], gid, hg, nullptr, NN);

    // classifier
    classify_kernel<<<GG, 128, 0, stream>>>(hg, wc1, bc1, wc2, bc2, outp);
}

// Round 12
// 213.560 us; speedup vs baseline: 1.0018x; 1.0018x over previous
//
#include <hip/hip_runtime.h>

#define NN 50000
#define EE 800000
#define HH 128
#define CC 10
#define GG 128
#define NBK 782      // ceil(NN/64) buckets = GEMM tiles
#define NCH 98       // ceil(EE/8192) edge chunks
#define CHUNK 8192

typedef __attribute__((ext_vector_type(8))) short short8;
typedef __attribute__((ext_vector_type(4))) float f32x4;

// ---------- bf16 helpers (RNE) ----------
__device__ __forceinline__ ushort f2b(float f) {
    union { float f; uint u; } x; x.f = f;
    uint u = x.u;
    uint r = (u + 0x7fffu + ((u >> 16) & 1u)) >> 16;
    return (ushort)r;
}
__device__ __forceinline__ float lo2f(uint v) {
    union { uint u; float f; } x; x.u = v << 16; return x.f;
}
__device__ __forceinline__ float hi2f(uint v) {
    union { uint u; float f; } x; x.u = v & 0xffff0000u; return x.f;
}

// ---------------- prep: f2b + wconv + hist + hg-zero + counter-zero -------------
// blocks [0,6250): f2b  [6250,6634): wconv  [6634,6732): hist  [6732,6796): hg=0

__global__ __launch_bounds__(256) void prep_kernel(const float* __restrict__ features,
                                                   const float* w0, const float* w1,
                                                   const float* w2, const float* w3,
                                                   const float* w4, const float* w5,
                                                   const int* __restrict__ dst,
                                                   ushort* __restrict__ hb0,
                                                   ushort* __restrict__ wt,
                                                   int* __restrict__ hist,
                                                   float* __restrict__ hg,
                                                   int* __restrict__ counter) {
    __shared__ int hc[NBK];
    const int b = blockIdx.x, t = threadIdx.x;
    if (b < 6250) {
        int idx = b * 256 + t;              // 1.6M quads exactly
        float4 v = *(const float4*)(features + (size_t)idx * 4);
        ushort4 o;
        o.x = f2b(v.x); o.y = f2b(v.y); o.z = f2b(v.z); o.w = f2b(v.w);
        *(ushort4*)(hb0 + (size_t)idx * 4) = o;
    } else if (b < 6634) {
        int idx = (b - 6250) * 256 + t;     // 0..98303
        int mi = idx >> 14, rest = idx & 16383;
        int n = rest >> 7, k = rest & 127;
        const float* src;
        switch (mi) {
            case 0: src = w0; break; case 1: src = w1; break;
            case 2: src = w2; break; case 3: src = w3; break;
            case 4: src = w4; break; default: src = w5; break;
        }
        wt[mi * 16384 + n * 128 + k] = f2b(src[k * 128 + n]);
    } else if (b < 6732) {
        const int c = b - 6634;
        for (int k = t; k < NBK; k += 256) hc[k] = 0;
        __syncthreads();
        for (int j = 0; j < 32; ++j) {
            int e = c * CHUNK + j * 256 + t;
            if (e < EE) atomicAdd(&hc[dst[e] >> 6], 1);
        }
        __syncthreads();
        for (int k = t; k < NBK; k += 256) hist[k * NCH + c] = hc[k];  // bucket-major
    } else {
        int idx = (b - 6732) * 256 + t;     // 16384 floats exactly
        hg[idx] = 0.f;
        if (b == 6732 && t == 0) *counter = 0;
    }
}

// per-bucket scan of chunk counts -> rel offsets; bucket base via atomic alloc
__global__ __launch_bounds__(128) void bscan_kernel(const int* __restrict__ hist,
                                                    int* __restrict__ rel,
                                                    int* __restrict__ btot,
                                                    int* __restrict__ bucketbase,
                                                    int* __restrict__ counter) {
    __shared__ int s[128];
    const int b = blockIdx.x, t = threadIdx.x;
    int v = (t < NCH) ? hist[b * NCH + t] : 0;
    s[t] = v;
    __syncthreads();
    for (int off = 1; off < 128; off <<= 1) {
        int tt = (t >= off) ? s[t - off] : 0;
        __syncthreads();
        s[t] += tt;
        __syncthreads();
    }
    if (t < NCH) rel[b * NCH + t] = s[t] - v;   // exclusive
    if (t == 127) {
        btot[b] = s[127];
        bucketbase[b] = atomicAdd(counter, s[127]);
    }
}

// scatter edges into bucket-contiguous packed lists: (dstLocal<<16)|src
__global__ __launch_bounds__(256) void scatter_kernel(const int* __restrict__ src,
                                                      const int* __restrict__ dst,
                                                      const int* __restrict__ rel,
                                                      const int* __restrict__ bucketbase,
                                                      int* __restrict__ epk) {
    __shared__ int cur[NBK];
    const int c = blockIdx.x, t = threadIdx.x;
    for (int k = t; k < NBK; k += 256) cur[k] = bucketbase[k] + rel[k * NCH + c];
    __syncthreads();
    for (int j = 0; j < 32; ++j) {
        int e = c * CHUNK + j * 256 + t;
        if (e < EE) {
            int d = dst[e];
            int bk = d >> 6;
            int pos = atomicAdd(&cur[bk], 1);
            epk[pos] = ((d & 63) << 16) | src[e];
        }
    }
}

// per-bucket counting sort -> node-ordered eidx + per-node [rowbeg,rowend)
__global__ __launch_bounds__(256) void bsort_kernel(const int* __restrict__ epk,
                                                    const int* __restrict__ bucketbase,
                                                    const int* __restrict__ btot,
                                                    ushort* __restrict__ eidx,
                                                    int* __restrict__ rowbeg,
                                                    int* __restrict__ rowend) {
    __shared__ int cnt[64];
    __shared__ int cur[64];
    const int b = blockIdx.x, t = threadIdx.x;
    const int base = bucketbase[b], end = base + btot[b];
    if (t < 64) cnt[t] = 0;
    __syncthreads();
    for (int i = base + t; i < end; i += 256)
        atomicAdd(&cnt[(epk[i] >> 16) & 63], 1);
    __syncthreads();
    if (t < 64) {
        int v = cnt[t];
        int incl = v;
#pragma unroll
        for (int off = 1; off < 64; off <<= 1) {
            int u = __shfl_up(incl, off);
            if (t >= off) incl += u;
        }
        int excl = incl - v;
        cur[t] = excl;
        int node = b * 64 + t;
        if (node < NN) {
            rowbeg[node] = base + excl;
            rowend[node] = base + incl;
        }
    }
    __syncthreads();
    for (int i = base + t; i < end; i += 256) {
        int p = epk[i];
        int dl = (p >> 16) & 63;
        int pos = atomicAdd(&cur[dl], 1);
        eidx[base + pos] = (ushort)(p & 0xffff);
    }
}

// ---------------- aggregation: half-wave per node, 8-deep + predicated tail --------
// xb[n] = bf16((1+eps)*h[n] + sum_neighbors h[s])

__global__ __launch_bounds__(256) void aggregate_kernel(const ushort* __restrict__ h,
                                                        const int* __restrict__ rowbeg,
                                                        const int* __restrict__ rowend,
                                                        const ushort* __restrict__ eidx,
                                                        const float* __restrict__ epsp,
                                                        int layer,
                                                        ushort* __restrict__ xb) {
    const int node = blockIdx.x * 8 + (threadIdx.x >> 5);
    if (node >= NN) return;
    const int li = threadIdx.x & 31;
    const int beg = rowbeg[node], end = rowend[node];
    float c0 = 0.f, c1 = 0.f, c2 = 0.f, c3 = 0.f;
    int i = beg;
    for (; i + 8 <= end; i += 8) {
        int s[8];
        uint2 v[8];
#pragma unroll
        for (int k = 0; k < 8; ++k) s[k] = eidx[i + k];
#pragma unroll
        for (int k = 0; k < 8; ++k)
            v[k] = *(const uint2*)(h + (size_t)s[k] * HH + li * 4);
#pragma unroll
        for (int k = 0; k < 8; ++k) {
            c0 += lo2f(v[k].x); c1 += hi2f(v[k].x);
            c2 += lo2f(v[k].y); c3 += hi2f(v[k].y);
        }
    }
    if (i < end) {
        int s[8];
        uint2 v[8];
#pragma unroll
        for (int k = 0; k < 8; ++k) {
            int idx = i + k;
            s[k] = eidx[idx < end ? idx : end - 1];
        }
#pragma unroll
        for (int k = 0; k < 8; ++k)
            v[k] = *(const uint2*)(h + (size_t)s[k] * HH + li * 4);
#pragma unroll
        for (int k = 0; k < 8; ++k) {
            if (i + k < end) {
                c0 += lo2f(v[k].x); c1 += hi2f(v[k].x);
                c2 += lo2f(v[k].y); c3 += hi2f(v[k].y);
            }
        }
    }
    uint2 hv = *(const uint2*)(h + (size_t)node * HH + li * 4);
    const float e = 1.0f + epsp[layer];
    ushort4 o;
    o.x = f2b(e * lo2f(hv.x) + c0);
    o.y = f2b(e * hi2f(hv.x) + c1);
    o.z = f2b(e * lo2f(hv.y) + c2);
    o.w = f2b(e * hi2f(hv.y) + c3);
    *(ushort4*)(xb + (size_t)node * HH + li * 4) = o;
}

// ---------------- fused MLP, 2-tile pipelined: 256 threads, 128 rows/block ------
// (R10 structure: 52KB LDS -> 3 blocks/CU; W once per block; tile1 stage loads
// issued under tile0 compute.) LAST: outputs -> xs LDS -> pooled into hg.

template <bool LAST>
__global__ __launch_bounds__(256) void fused_mlp(const ushort* __restrict__ xb,
                                                 const ushort* __restrict__ wt1,  // [n][k]
                                                 const ushort* __restrict__ wt2,  // [n][k]
                                                 const float* __restrict__ b1,
                                                 const float* __restrict__ b2,
                                                 const int* __restrict__ gid,
                                                 float* __restrict__ hg,
                                                 ushort* __restrict__ out, int nrows) {
    __shared__ __align__(16) ushort xs[2][64][136];
    __shared__ __align__(16) ushort hs[64][136];
    const int tid = threadIdx.x;
    const int lane = tid & 63, w = tid >> 6;
    const int row0 = blockIdx.x * 128;
    const int l15 = lane & 15, lhi = lane >> 4;
    const int sr = tid >> 4, skq = tid & 15;

    // ---- stage tile0 loads (HBM critical path first) ----
    uint4 st[4];
#pragma unroll
    for (int it = 0; it < 4; ++it) {
        int r = it * 16 + sr;
        int row = row0 + r;
        st[it] = make_uint4(0u, 0u, 0u, 0u);
        if (row < nrows) st[it] = *(const uint4*)(xb + (size_t)row * HH + skq * 8);
    }

    // ---- W fragments (L2), once per block ----
    short8 a1[2][4], a2[2][4];
#pragma unroll
    for (int fa = 0; fa < 2; ++fa)
#pragma unroll
        for (int kt = 0; kt < 4; ++kt) {
            int n = w * 32 + fa * 16 + l15;
            int k = kt * 32 + lhi * 8;
            a1[fa][kt] = *(const short8*)(wt1 + n * HH + k);
            a2[fa][kt] = *(const short8*)(wt2 + n * HH + k);
        }

#pragma unroll
    for (int it = 0; it < 4; ++it) *(uint4*)&xs[0][it * 16 + sr][skq * 8] = st[it];
    __syncthreads();

    // ---- issue tile1 stage loads (latency hides under tile0 GEMMs) ----
#pragma unroll
    for (int it = 0; it < 4; ++it) {
        int r = it * 16 + sr;
        int row = row0 + 64 + r;
        st[it] = make_uint4(0u, 0u, 0u, 0u);
        if (row < nrows) st[it] = *(const uint4*)(xb + (size_t)row * HH + skq * 8);
    }

    f32x4 acc[2][4];
#pragma unroll
    for (int tile = 0; tile < 2; ++tile) {
        const int rt0 = row0 + tile * 64;
        // ---- GEMM1 ----
#pragma unroll
        for (int fa = 0; fa < 2; ++fa)
#pragma unroll
            for (int fb = 0; fb < 4; ++fb) acc[fa][fb] = (f32x4)(0.f);
#pragma unroll
        for (int kt = 0; kt < 4; ++kt) {
            short8 bfr[4];
#pragma unroll
            for (int fb = 0; fb < 4; ++fb)
                bfr[fb] = *(const short8*)&xs[tile][fb * 16 + l15][kt * 32 + lhi * 8];
#pragma unroll
            for (int fa = 0; fa < 2; ++fa)
#pragma unroll
                for (int fb = 0; fb < 4; ++fb)
                    acc[fa][fb] = __builtin_amdgcn_mfma_f32_16x16x32_bf16(a1[fa][kt], bfr[fb],
                                                                         acc[fa][fb], 0, 0, 0);
        }
        // hidden = relu(acc+b1) -> hs
#pragma unroll
        for (int fa = 0; fa < 2; ++fa) {
            int nb = w * 32 + fa * 16 + lhi * 4;
            float4 bv = *(const float4*)(b1 + nb);
#pragma unroll
            for (int fb = 0; fb < 4; ++fb) {
                ushort4 o;
                o.x = f2b(fmaxf(acc[fa][fb][0] + bv.x, 0.f));
                o.y = f2b(fmaxf(acc[fa][fb][1] + bv.y, 0.f));
                o.z = f2b(fmaxf(acc[fa][fb][2] + bv.z, 0.f));
                o.w = f2b(fmaxf(acc[fa][fb][3] + bv.w, 0.f));
                *(ushort4*)&hs[fb * 16 + l15][nb] = o;
            }
        }
        __syncthreads();
        // ---- GEMM2 ----
#pragma unroll
        for (int fa = 0; fa < 2; ++fa)
#pragma unroll
            for (int fb = 0; fb < 4; ++fb) acc[fa][fb] = (f32x4)(0.f);
#pragma unroll
        for (int kt = 0; kt < 4; ++kt) {
            short8 bfr[4];
#pragma unroll
            for (int fb = 0; fb < 4; ++fb)
                bfr[fb] = *(const short8*)&hs[fb * 16 + l15][kt * 32 + lhi * 8];
#pragma unroll
            for (int fa = 0; fa < 2; ++fa)
#pragma unroll
                for (int fb = 0; fb < 4; ++fb)
                    acc[fa][fb] = __builtin_amdgcn_mfma_f32_16x16x32_bf16(a2[fa][kt], bfr[fb],
                                                                         acc[fa][fb], 0, 0, 0);
        }
        // ---- epilogue ----
#pragma unroll
        for (int fa = 0; fa < 2; ++fa) {
            int nb = w * 32 + fa * 16 + lhi * 4;
            float4 bv = *(const float4*)(b2 + nb);
#pragma unroll
            for (int fb = 0; fb < 4; ++fb) {
                int m = rt0 + fb * 16 + l15;
                ushort4 o;
                o.x = f2b(fmaxf(acc[fa][fb][0] + bv.x, 0.f));
                o.y = f2b(fmaxf(acc[fa][fb][1] + bv.y, 0.f));
                o.z = f2b(fmaxf(acc[fa][fb][2] + bv.z, 0.f));
                o.w = f2b(fmaxf(acc[fa][fb][3] + bv.w, 0.f));
                if (LAST) {
                    *(ushort4*)&xs[tile][fb * 16 + l15][nb] = o;  // xs[tile] free after GEMM1
                } else if (m < nrows) {
                    *(ushort4*)(out + (size_t)m * HH + nb) = o;
                }
            }
        }
        if (tile == 0) {
            // tile1's xs write: loads completed under tile0 compute
#pragma unroll
            for (int it = 0; it < 4; ++it) *(uint4*)&xs[1][it * 16 + sr][skq * 8] = st[it];
        }
        __syncthreads();   // hs reads done before next tile's hs write; xs[1]/LAST-xs visible
        if (LAST) {
            // pool tile's 64 rows from xs[tile] into hg
            int j = tid & 63;
            int rg = tid >> 6;
            float ax = 0.f, ay = 0.f;
            int gcur = -1;
#pragma unroll
            for (int ii = 0; ii < 16; ++ii) {
                int r = rg + ii * 4;
                int n = rt0 + r;
                if (n >= nrows) break;
                int g = gid[n];
                if (g != gcur) {
                    if (gcur >= 0) {
                        atomicAdd(&hg[gcur * HH + 2 * j], ax);
                        atomicAdd(&hg[gcur * HH + 2 * j + 1], ay);
                    }
                    gcur = g; ax = 0.f; ay = 0.f;
                }
                uint v = *(const uint*)&xs[tile][r][2 * j];
                ax += lo2f(v); ay += hi2f(v);
            }
            if (gcur >= 0) {
                atomicAdd(&hg[gcur * HH + 2 * j], ax);
                atomicAdd(&hg[gcur * HH + 2 * j + 1], ay);
            }
        }
    }
}

// ---------------- classifier head (fp32) ----------------

__global__ __launch_bounds__(128) void classify_kernel(const float* __restrict__ hg,
                                                       const float* __restrict__ wc1,
                                                       const float* __restrict__ bc1,
                                                       const float* __restrict__ wc2,
                                                       const float* __restrict__ bc2,
                                                       float* __restrict__ out) {
    __shared__ float xrow[HH];
    __shared__ float trow[HH];
    int g = blockIdx.x, j = threadIdx.x;
    xrow[j] = hg[g * HH + j];
    __syncthreads();
    float s = bc1[j];
#pragma unroll 8
    for (int k = 0; k < HH; ++k) s += xrow[k] * wc1[k * HH + j];
    trow[j] = fmaxf(s, 0.f);
    __syncthreads();
    if (j < CC) {
        float o = bc2[j];
#pragma unroll 8
        for (int k = 0; k < HH; ++k) o += trow[k] * wc2[k * CC + j];
        out[g * CC + j] = o;
    }
}

extern "C" void kernel_launch(void* const* d_in, const int* in_sizes, int n_in,
                              void* d_out, int out_size, void* d_ws, size_t ws_size,
                              hipStream_t stream) {
    const float* features = (const float*)d_in[0];
    const int* src = (const int*)d_in[1];
    const int* dst = (const int*)d_in[2];
    const int* gid = (const int*)d_in[3];
    const float* eps = (const float*)d_in[4];
    const float* w1[3] = {(const float*)d_in[5], (const float*)d_in[9], (const float*)d_in[13]};
    const float* b1[3] = {(const float*)d_in[6], (const float*)d_in[10], (const float*)d_in[14]};
    const float* w2[3] = {(const float*)d_in[7], (const float*)d_in[11], (const float*)d_in[15]};
    const float* b2[3] = {(const float*)d_in[8], (const float*)d_in[12], (const float*)d_in[16]};
    const float* wc1 = (const float*)d_in[17];
    const float* bc1 = (const float*)d_in[18];
    const float* wc2 = (const float*)d_in[19];
    const float* bc2 = (const float*)d_in[20];
    float* outp = (float*)d_out;

    char* ws = (char*)d_ws;
    size_t off = 0;
    auto alloc = [&](size_t bytes) {
        void* p = ws + off;
        off += (bytes + 255) & ~(size_t)255;
        return p;
    };
    int* hist = (int*)alloc((size_t)NBK * NCH * sizeof(int));
    int* rel = (int*)alloc((size_t)NBK * NCH * sizeof(int));
    int* btot = (int*)alloc(NBK * sizeof(int));
    int* bucketbase = (int*)alloc(NBK * sizeof(int));
    int* counter = (int*)alloc(256);
    int* epk = (int*)alloc(EE * sizeof(int));
    ushort* eidx = (ushort*)alloc(EE * sizeof(ushort));
    int* rowbeg = (int*)alloc(NN * sizeof(int));
    int* rowend = (int*)alloc(NN * sizeof(int));
    ushort* hb0 = (ushort*)alloc((size_t)NN * HH * 2);    // features bf16
    ushort* hbuf = (ushort*)alloc((size_t)NN * HH * 2);   // layer h bf16
    ushort* xb = (ushort*)alloc((size_t)NN * HH * 2);     // combined MLP input bf16
    ushort* wtb = (ushort*)alloc(6 * 16384 * 2);          // transposed bf16 weights
    float* hg = (float*)alloc(GG * HH * sizeof(float));

    // prep (f2b + wconv + hist + hg/counter zero) then bucketed CSR build
    prep_kernel<<<6796, 256, 0, stream>>>(features, w1[0], w2[0], w1[1], w2[1], w1[2], w2[2],
                                          dst, hb0, wtb, hist, hg, counter);
    bscan_kernel<<<NBK, 128, 0, stream>>>(hist, rel, btot, bucketbase, counter);
    scatter_kernel<<<NCH, 256, 0, stream>>>(src, dst, rel, bucketbase, epk);
    bsort_kernel<<<NBK, 256, 0, stream>>>(epk, bucketbase, btot, eidx, rowbeg, rowend);

    const int GB = (NN + 127) / 128;  // 391
    const int AB = (NN + 7) / 8;      // 6250

    // layer 1
    aggregate_kernel<<<AB, 256, 0, stream>>>(hb0, rowbeg, rowend, eidx, eps, 0, xb);
    fused_mlp<false><<<GB, 256, 0, stream>>>(xb, wtb + 0 * 16384, wtb + 1 * 16384,
                                             b1[0], b2[0], gid, hg, hbuf, NN);
    // layer 2
    aggregate_kernel<<<AB, 256, 0, stream>>>(hbuf, rowbeg, rowend, eidx, eps, 1, xb);
    fused_mlp<false><<<GB, 256, 0, stream>>>(xb, wtb + 2 * 16384, wtb + 3 * 16384,
                                             b1[1], b2[1], gid, hg, hbuf, NN);
    // layer 3 (pool fused into epilogue; no h write)
    aggregate_kernel<<<AB, 256, 0, stream>>>(hbuf, rowbeg, rowend, eidx, eps, 2, xb);
    fused_mlp<true><<<GB, 256, 0, stream>>>(xb, wtb + 4 * 16384, wtb + 5 * 16384,
                                            b1[2], b2[2], gid, hg, nullptr, NN);

    // classifier
    classify_kernel<<<GG, 128, 0, stream>>>(hg, wc1, bc1, wc2, bc2, outp);
}

// Round 13
// 204.472 us; speedup vs baseline: 1.0463x; 1.0444x over previous
//
#include <hip/hip_runtime.h>

#define NN 50000
#define EE 800000
#define HH 128
#define CC 10
#define GG 128
#define NBK 782      // ceil(NN/64) buckets = GEMM tiles
#define NCH 98       // ceil(EE/8192) edge chunks
#define CHUNK 8192
#define BCAP 2048    // fixed bucket capacity (mean 1023, sigma~32 -> >30 sigma margin)

typedef __attribute__((ext_vector_type(8))) short short8;
typedef __attribute__((ext_vector_type(4))) float f32x4;

// ---------- bf16 helpers (RNE) ----------
__device__ __forceinline__ ushort f2b(float f) {
    union { float f; uint u; } x; x.f = f;
    uint u = x.u;
    uint r = (u + 0x7fffu + ((u >> 16) & 1u)) >> 16;
    return (ushort)r;
}
__device__ __forceinline__ float lo2f(uint v) {
    union { uint u; float f; } x; x.u = v << 16; return x.f;
}
__device__ __forceinline__ float hi2f(uint v) {
    union { uint u; float f; } x; x.u = v & 0xffff0000u; return x.f;
}

// ---------------- prep: f2b + wconv + hist + hg-zero ----------------------------
// blocks [0,6250): f2b  [6250,6634): wconv  [6634,6732): hist  [6732,6796): hg=0

__global__ __launch_bounds__(256) void prep_kernel(const float* __restrict__ features,
                                                   const float* w0, const float* w1,
                                                   const float* w2, const float* w3,
                                                   const float* w4, const float* w5,
                                                   const int* __restrict__ dst,
                                                   ushort* __restrict__ hb0,
                                                   ushort* __restrict__ wt,
                                                   int* __restrict__ hist,
                                                   float* __restrict__ hg) {
    __shared__ int hc[NBK];
    const int b = blockIdx.x, t = threadIdx.x;
    if (b < 6250) {
        int idx = b * 256 + t;              // 1.6M quads exactly
        float4 v = *(const float4*)(features + (size_t)idx * 4);
        ushort4 o;
        o.x = f2b(v.x); o.y = f2b(v.y); o.z = f2b(v.z); o.w = f2b(v.w);
        *(ushort4*)(hb0 + (size_t)idx * 4) = o;
    } else if (b < 6634) {
        int idx = (b - 6250) * 256 + t;     // 0..98303
        int mi = idx >> 14, rest = idx & 16383;
        int n = rest >> 7, k = rest & 127;
        const float* src;
        switch (mi) {
            case 0: src = w0; break; case 1: src = w1; break;
            case 2: src = w2; break; case 3: src = w3; break;
            case 4: src = w4; break; default: src = w5; break;
        }
        wt[mi * 16384 + n * 128 + k] = f2b(src[k * 128 + n]);
    } else if (b < 6732) {
        const int c = b - 6634;
        for (int k = t; k < NBK; k += 256) hc[k] = 0;
        __syncthreads();
        for (int j = 0; j < 32; ++j) {
            int e = c * CHUNK + j * 256 + t;
            if (e < EE) atomicAdd(&hc[dst[e] >> 6], 1);
        }
        __syncthreads();
        for (int k = t; k < NBK; k += 256) hist[k * NCH + c] = hc[k];  // bucket-major
    } else {
        int idx = (b - 6732) * 256 + t;     // 16384 floats exactly
        hg[idx] = 0.f;
    }
}

// per-bucket scan of chunk counts -> rel offsets + bucket totals (static bases)
__global__ __launch_bounds__(128) void bscan_kernel(const int* __restrict__ hist,
                                                    int* __restrict__ rel,
                                                    int* __restrict__ btot) {
    __shared__ int s[128];
    const int b = blockIdx.x, t = threadIdx.x;
    int v = (t < NCH) ? hist[b * NCH + t] : 0;
    s[t] = v;
    __syncthreads();
    for (int off = 1; off < 128; off <<= 1) {
        int tt = (t >= off) ? s[t - off] : 0;
        __syncthreads();
        s[t] += tt;
        __syncthreads();
    }
    if (t < NCH) rel[b * NCH + t] = s[t] - v;   // exclusive
    if (t == 127) btot[b] = s[127];
}

// scatter edges into fixed-capacity bucket regions: (dstLocal<<16)|src
__global__ __launch_bounds__(256) void scatter_kernel(const int* __restrict__ src,
                                                      const int* __restrict__ dst,
                                                      const int* __restrict__ rel,
                                                      int* __restrict__ epk) {
    __shared__ int cur[NBK];
    const int c = blockIdx.x, t = threadIdx.x;
    for (int k = t; k < NBK; k += 256) cur[k] = k * BCAP + rel[k * NCH + c];
    __syncthreads();
    for (int j = 0; j < 32; ++j) {
        int e = c * CHUNK + j * 256 + t;
        if (e < EE) {
            int d = dst[e];
            int bk = d >> 6;
            int pos = atomicAdd(&cur[bk], 1);
            epk[pos] = ((d & 63) << 16) | src[e];
        }
    }
}

// per-bucket counting sort -> node-ordered eidx + per-node [rowbeg,rowend)
__global__ __launch_bounds__(256) void bsort_kernel(const int* __restrict__ epk,
                                                    const int* __restrict__ btot,
                                                    ushort* __restrict__ eidx,
                                                    int* __restrict__ rowbeg,
                                                    int* __restrict__ rowend) {
    __shared__ int cnt[64];
    __shared__ int cur[64];
    const int b = blockIdx.x, t = threadIdx.x;
    const int base = b * BCAP, end = base + btot[b];
    if (t < 64) cnt[t] = 0;
    __syncthreads();
    for (int i = base + t; i < end; i += 256)
        atomicAdd(&cnt[(epk[i] >> 16) & 63], 1);
    __syncthreads();
    if (t < 64) {
        int v = cnt[t];
        int incl = v;
#pragma unroll
        for (int off = 1; off < 64; off <<= 1) {
            int u = __shfl_up(incl, off);
            if (t >= off) incl += u;
        }
        int excl = incl - v;
        cur[t] = excl;
        int node = b * 64 + t;
        if (node < NN) {
            rowbeg[node] = base + excl;
            rowend[node] = base + incl;
        }
    }
    __syncthreads();
    for (int i = base + t; i < end; i += 256) {
        int p = epk[i];
        int dl = (p >> 16) & 63;
        int pos = atomicAdd(&cur[dl], 1);
        eidx[base + pos] = (ushort)(p & 0xffff);
    }
}

// ---------------- aggregation: half-wave per node, 8-deep + predicated tail --------
// xb[n] = bf16((1+eps)*h[n] + sum_neighbors h[s])

__global__ __launch_bounds__(256) void aggregate_kernel(const ushort* __restrict__ h,
                                                        const int* __restrict__ rowbeg,
                                                        const int* __restrict__ rowend,
                                                        const ushort* __restrict__ eidx,
                                                        const float* __restrict__ epsp,
                                                        int layer,
                                                        ushort* __restrict__ xb) {
    const int node = blockIdx.x * 8 + (threadIdx.x >> 5);
    if (node >= NN) return;
    const int li = threadIdx.x & 31;
    const int beg = rowbeg[node], end = rowend[node];
    float c0 = 0.f, c1 = 0.f, c2 = 0.f, c3 = 0.f;
    int i = beg;
    for (; i + 8 <= end; i += 8) {
        int s[8];
        uint2 v[8];
#pragma unroll
        for (int k = 0; k < 8; ++k) s[k] = eidx[i + k];
#pragma unroll
        for (int k = 0; k < 8; ++k)
            v[k] = *(const uint2*)(h + (size_t)s[k] * HH + li * 4);
#pragma unroll
        for (int k = 0; k < 8; ++k) {
            c0 += lo2f(v[k].x); c1 += hi2f(v[k].x);
            c2 += lo2f(v[k].y); c3 += hi2f(v[k].y);
        }
    }
    if (i < end) {
        int s[8];
        uint2 v[8];
#pragma unroll
        for (int k = 0; k < 8; ++k) {
            int idx = i + k;
            s[k] = eidx[idx < end ? idx : end - 1];
        }
#pragma unroll
        for (int k = 0; k < 8; ++k)
            v[k] = *(const uint2*)(h + (size_t)s[k] * HH + li * 4);
#pragma unroll
        for (int k = 0; k < 8; ++k) {
            if (i + k < end) {
                c0 += lo2f(v[k].x); c1 += hi2f(v[k].x);
                c2 += lo2f(v[k].y); c3 += hi2f(v[k].y);
            }
        }
    }
    uint2 hv = *(const uint2*)(h + (size_t)node * HH + li * 4);
    const float e = 1.0f + epsp[layer];
    ushort4 o;
    o.x = f2b(e * lo2f(hv.x) + c0);
    o.y = f2b(e * hi2f(hv.x) + c1);
    o.z = f2b(e * lo2f(hv.y) + c2);
    o.w = f2b(e * hi2f(hv.y) + c3);
    *(ushort4*)(xb + (size_t)node * HH + li * 4) = o;
}

// ---------------- fused MLP, 2-tile pipelined: 256 threads, 128 rows/block ------
// (R10 structure: 52KB LDS -> 3 blocks/CU; W once per block; tile1 stage loads
// issued under tile0 compute.) LAST: outputs -> xs LDS -> pooled into hg.

template <bool LAST>
__global__ __launch_bounds__(256) void fused_mlp(const ushort* __restrict__ xb,
                                                 const ushort* __restrict__ wt1,  // [n][k]
                                                 const ushort* __restrict__ wt2,  // [n][k]
                                                 const float* __restrict__ b1,
                                                 const float* __restrict__ b2,
                                                 const int* __restrict__ gid,
                                                 float* __restrict__ hg,
                                                 ushort* __restrict__ out, int nrows) {
    __shared__ __align__(16) ushort xs[2][64][136];
    __shared__ __align__(16) ushort hs[64][136];
    const int tid = threadIdx.x;
    const int lane = tid & 63, w = tid >> 6;
    const int row0 = blockIdx.x * 128;
    const int l15 = lane & 15, lhi = lane >> 4;
    const int sr = tid >> 4, skq = tid & 15;

    // ---- stage tile0 loads (HBM critical path first) ----
    uint4 st[4];
#pragma unroll
    for (int it = 0; it < 4; ++it) {
        int r = it * 16 + sr;
        int row = row0 + r;
        st[it] = make_uint4(0u, 0u, 0u, 0u);
        if (row < nrows) st[it] = *(const uint4*)(xb + (size_t)row * HH + skq * 8);
    }

    // ---- W fragments (L2), once per block ----
    short8 a1[2][4], a2[2][4];
#pragma unroll
    for (int fa = 0; fa < 2; ++fa)
#pragma unroll
        for (int kt = 0; kt < 4; ++kt) {
            int n = w * 32 + fa * 16 + l15;
            int k = kt * 32 + lhi * 8;
            a1[fa][kt] = *(const short8*)(wt1 + n * HH + k);
            a2[fa][kt] = *(const short8*)(wt2 + n * HH + k);
        }

#pragma unroll
    for (int it = 0; it < 4; ++it) *(uint4*)&xs[0][it * 16 + sr][skq * 8] = st[it];
    __syncthreads();

    // ---- issue tile1 stage loads (latency hides under tile0 GEMMs) ----
#pragma unroll
    for (int it = 0; it < 4; ++it) {
        int r = it * 16 + sr;
        int row = row0 + 64 + r;
        st[it] = make_uint4(0u, 0u, 0u, 0u);
        if (row < nrows) st[it] = *(const uint4*)(xb + (size_t)row * HH + skq * 8);
    }

    f32x4 acc[2][4];
#pragma unroll
    for (int tile = 0; tile < 2; ++tile) {
        const int rt0 = row0 + tile * 64;
        // ---- GEMM1 ----
#pragma unroll
        for (int fa = 0; fa < 2; ++fa)
#pragma unroll
            for (int fb = 0; fb < 4; ++fb) acc[fa][fb] = (f32x4)(0.f);
#pragma unroll
        for (int kt = 0; kt < 4; ++kt) {
            short8 bfr[4];
#pragma unroll
            for (int fb = 0; fb < 4; ++fb)
                bfr[fb] = *(const short8*)&xs[tile][fb * 16 + l15][kt * 32 + lhi * 8];
#pragma unroll
            for (int fa = 0; fa < 2; ++fa)
#pragma unroll
                for (int fb = 0; fb < 4; ++fb)
                    acc[fa][fb] = __builtin_amdgcn_mfma_f32_16x16x32_bf16(a1[fa][kt], bfr[fb],
                                                                         acc[fa][fb], 0, 0, 0);
        }
        // hidden = relu(acc+b1) -> hs
#pragma unroll
        for (int fa = 0; fa < 2; ++fa) {
            int nb = w * 32 + fa * 16 + lhi * 4;
            float4 bv = *(const float4*)(b1 + nb);
#pragma unroll
            for (int fb = 0; fb < 4; ++fb) {
                ushort4 o;
                o.x = f2b(fmaxf(acc[fa][fb][0] + bv.x, 0.f));
                o.y = f2b(fmaxf(acc[fa][fb][1] + bv.y, 0.f));
                o.z = f2b(fmaxf(acc[fa][fb][2] + bv.z, 0.f));
                o.w = f2b(fmaxf(acc[fa][fb][3] + bv.w, 0.f));
                *(ushort4*)&hs[fb * 16 + l15][nb] = o;
            }
        }
        __syncthreads();
        // ---- GEMM2 ----
#pragma unroll
        for (int fa = 0; fa < 2; ++fa)
#pragma unroll
            for (int fb = 0; fb < 4; ++fb) acc[fa][fb] = (f32x4)(0.f);
#pragma unroll
        for (int kt = 0; kt < 4; ++kt) {
            short8 bfr[4];
#pragma unroll
            for (int fb = 0; fb < 4; ++fb)
                bfr[fb] = *(const short8*)&hs[fb * 16 + l15][kt * 32 + lhi * 8];
#pragma unroll
            for (int fa = 0; fa < 2; ++fa)
#pragma unroll
                for (int fb = 0; fb < 4; ++fb)
                    acc[fa][fb] = __builtin_amdgcn_mfma_f32_16x16x32_bf16(a2[fa][kt], bfr[fb],
                                                                         acc[fa][fb], 0, 0, 0);
        }
        // ---- epilogue ----
#pragma unroll
        for (int fa = 0; fa < 2; ++fa) {
            int nb = w * 32 + fa * 16 + lhi * 4;
            float4 bv = *(const float4*)(b2 + nb);
#pragma unroll
            for (int fb = 0; fb < 4; ++fb) {
                int m = rt0 + fb * 16 + l15;
                ushort4 o;
                o.x = f2b(fmaxf(acc[fa][fb][0] + bv.x, 0.f));
                o.y = f2b(fmaxf(acc[fa][fb][1] + bv.y, 0.f));
                o.z = f2b(fmaxf(acc[fa][fb][2] + bv.z, 0.f));
                o.w = f2b(fmaxf(acc[fa][fb][3] + bv.w, 0.f));
                if (LAST) {
                    *(ushort4*)&xs[tile][fb * 16 + l15][nb] = o;  // xs[tile] free after GEMM1
                } else if (m < nrows) {
                    *(ushort4*)(out + (size_t)m * HH + nb) = o;
                }
            }
        }
        if (tile == 0) {
            // tile1's xs write: loads completed under tile0 compute
#pragma unroll
            for (int it = 0; it < 4; ++it) *(uint4*)&xs[1][it * 16 + sr][skq * 8] = st[it];
        }
        __syncthreads();   // hs reads done before next tile's hs write; xs[1]/LAST-xs visible
        if (LAST) {
            // pool tile's 64 rows from xs[tile] into hg
            int j = tid & 63;
            int rg = tid >> 6;
            float ax = 0.f, ay = 0.f;
            int gcur = -1;
#pragma unroll
            for (int ii = 0; ii < 16; ++ii) {
                int r = rg + ii * 4;
                int n = rt0 + r;
                if (n >= nrows) break;
                int g = gid[n];
                if (g != gcur) {
                    if (gcur >= 0) {
                        atomicAdd(&hg[gcur * HH + 2 * j], ax);
                        atomicAdd(&hg[gcur * HH + 2 * j + 1], ay);
                    }
                    gcur = g; ax = 0.f; ay = 0.f;
                }
                uint v = *(const uint*)&xs[tile][r][2 * j];
                ax += lo2f(v); ay += hi2f(v);
            }
            if (gcur >= 0) {
                atomicAdd(&hg[gcur * HH + 2 * j], ax);
                atomicAdd(&hg[gcur * HH + 2 * j + 1], ay);
            }
        }
    }
}

// ---------------- classifier head (fp32) ----------------

__global__ __launch_bounds__(128) void classify_kernel(const float* __restrict__ hg,
                                                       const float* __restrict__ wc1,
                                                       const float* __restrict__ bc1,
                                                       const float* __restrict__ wc2,
                                                       const float* __restrict__ bc2,
                                                       float* __restrict__ out) {
    __shared__ float xrow[HH];
    __shared__ float trow[HH];
    int g = blockIdx.x, j = threadIdx.x;
    xrow[j] = hg[g * HH + j];
    __syncthreads();
    float s = bc1[j];
#pragma unroll 8
    for (int k = 0; k < HH; ++k) s += xrow[k] * wc1[k * HH + j];
    trow[j] = fmaxf(s, 0.f);
    __syncthreads();
    if (j < CC) {
        float o = bc2[j];
#pragma unroll 8
        for (int k = 0; k < HH; ++k) o += trow[k] * wc2[k * CC + j];
        out[g * CC + j] = o;
    }
}

extern "C" void kernel_launch(void* const* d_in, const int* in_sizes, int n_in,
                              void* d_out, int out_size, void* d_ws, size_t ws_size,
                              hipStream_t stream) {
    const float* features = (const float*)d_in[0];
    const int* src = (const int*)d_in[1];
    const int* dst = (const int*)d_in[2];
    const int* gid = (const int*)d_in[3];
    const float* eps = (const float*)d_in[4];
    const float* w1[3] = {(const float*)d_in[5], (const float*)d_in[9], (const float*)d_in[13]};
    const float* b1[3] = {(const float*)d_in[6], (const float*)d_in[10], (const float*)d_in[14]};
    const float* w2[3] = {(const float*)d_in[7], (const float*)d_in[11], (const float*)d_in[15]};
    const float* b2[3] = {(const float*)d_in[8], (const float*)d_in[12], (const float*)d_in[16]};
    const float* wc1 = (const float*)d_in[17];
    const float* bc1 = (const float*)d_in[18];
    const float* wc2 = (const float*)d_in[19];
    const float* bc2 = (const float*)d_in[20];
    float* outp = (float*)d_out;

    char* ws = (char*)d_ws;
    size_t off = 0;
    auto alloc = [&](size_t bytes) {
        void* p = ws + off;
        off += (bytes + 255) & ~(size_t)255;
        return p;
    };
    int* hist = (int*)alloc((size_t)NBK * NCH * sizeof(int));
    int* rel = (int*)alloc((size_t)NBK * NCH * sizeof(int));
    int* btot = (int*)alloc(NBK * sizeof(int));
    int* epk = (int*)alloc((size_t)NBK * BCAP * sizeof(int));
    ushort* eidx = (ushort*)alloc((size_t)NBK * BCAP * sizeof(ushort));
    int* rowbeg = (int*)alloc(NN * sizeof(int));
    int* rowend = (int*)alloc(NN * sizeof(int));
    ushort* hb0 = (ushort*)alloc((size_t)NN * HH * 2);    // features bf16
    ushort* hbuf = (ushort*)alloc((size_t)NN * HH * 2);   // layer h bf16
    ushort* xb = (ushort*)alloc((size_t)NN * HH * 2);     // combined MLP input bf16
    ushort* wtb = (ushort*)alloc(6 * 16384 * 2);          // transposed bf16 weights
    float* hg = (float*)alloc(GG * HH * sizeof(float));

    // prep (f2b + wconv + hist + hg zero) then bucketed build (static bucket bases)
    prep_kernel<<<6796, 256, 0, stream>>>(features, w1[0], w2[0], w1[1], w2[1], w1[2], w2[2],
                                          dst, hb0, wtb, hist, hg);
    bscan_kernel<<<NBK, 128, 0, stream>>>(hist, rel, btot);
    scatter_kernel<<<NCH, 256, 0, stream>>>(src, dst, rel, epk);
    bsort_kernel<<<NBK, 256, 0, stream>>>(epk, btot, eidx, rowbeg, rowend);

    const int GB = (NN + 127) / 128;  // 391
    const int AB = (NN + 7) / 8;      // 6250

    // layer 1
    aggregate_kernel<<<AB, 256, 0, stream>>>(hb0, rowbeg, rowend, eidx, eps, 0, xb);
    fused_mlp<false><<<GB, 256, 0, stream>>>(xb, wtb + 0 * 16384, wtb + 1 * 16384,
                                             b1[0], b2[0], gid, hg, hbuf, NN);
    // layer 2
    aggregate_kernel<<<AB, 256, 0, stream>>>(hbuf, rowbeg, rowend, eidx, eps, 1, xb);
    fused_mlp<false><<<GB, 256, 0, stream>>>(xb, wtb + 2 * 16384, wtb + 3 * 16384,
                                             b1[1], b2[1], gid, hg, hbuf, NN);
    // layer 3 (pool fused into epilogue; no h write)
    aggregate_kernel<<<AB, 256, 0, stream>>>(hbuf, rowbeg, rowend, eidx, eps, 2, xb);
    fused_mlp<true><<<GB, 256, 0, stream>>>(xb, wtb + 4 * 16384, wtb + 5 * 16384,
                                            b1[2], b2[2], gid, hg, nullptr, NN);

    // classifier
    classify_kernel<<<GG, 128, 0, stream>>>(hg, wc1, bc1, wc2, bc2, outp);
}